// Round 19
// baseline (127.151 us; speedup 1.0000x reference)
//
#include <hip/hip_runtime.h>

namespace {

typedef float  f32x4  __attribute__((ext_vector_type(4)));
typedef float  f32x16 __attribute__((ext_vector_type(16)));
typedef short  bf16x8 __attribute__((ext_vector_type(8)));
typedef int    i32x4  __attribute__((ext_vector_type(4)));
typedef unsigned int u32;

constexpr int kRows  = 524288;
constexpr int kCont  = 64;
constexpr int kNCate = 16;
constexpr int kVocab = 1000;
constexpr int kEm    = 8;
constexpr int kRH    = 32;
constexpr int kPH    = 16;

constexpr int    kNFrag = 48;
constexpr size_t kOffEH = (size_t)kNFrag * 1024;        // 49152
constexpr size_t kOffHG = kOffEH + 256000;              // HG: 8*32*16 f32 = 16KB
constexpr size_t kOffHB = kOffHG + 16384;               // Hb1p: 128 f32

__device__ inline u32 rne_hi(float x) {
    u32 u = __float_as_uint(x);
    return ((u + 0x7fffu + ((u >> 16) & 1u)) >> 16) & 0xffffu;
}
__device__ inline float hi_f32(u32 h) { return __uint_as_float(h << 16); }
__device__ inline u32 pack2(float a, float b) {
    return rne_hi(a) | (rne_hi(b) << 16);
}

union FragU { u32 w[4]; bf16x8 v; uint4 u4; };

__device__ inline f32x16 mfma16(bf16x8 a, bf16x8 b, f32x16 c) {
    return __builtin_amdgcn_mfma_f32_32x32x16_bf16(a, b, c, 0, 0, 0);
}
__device__ inline f32x16 zero16() {
    f32x16 z;
#pragma unroll
    for (int i = 0; i < 16; ++i) z[i] = 0.f;
    return z;
}
__device__ inline void gload_lds16(const void* g, void* l) {
    __builtin_amdgcn_global_load_lds(
        (const __attribute__((address_space(1))) void*)g,
        (__attribute__((address_space(3))) void*)l, 16, 0, 0);
}
__device__ inline void fence_vm0() {
    asm volatile("s_waitcnt vmcnt(0)" ::: "memory");
    __builtin_amdgcn_sched_barrier(0);
}
__device__ inline void fence_lgkm0() {
    asm volatile("s_waitcnt lgkmcnt(0)" ::: "memory");
    __builtin_amdgcn_sched_barrier(0);
}

// ---------------------------------------------------------------------------
// Pre-kernel 0 (R17, unchanged): fold layer 3 into heads.
// ---------------------------------------------------------------------------
__global__ __launch_bounds__(256) void build_hg(
    const float* __restrict__ W3, const float* __restrict__ HW1,
    const float* __restrict__ b3, const float* __restrict__ Hb1,
    float* __restrict__ HG, float* __restrict__ Hb1p)
{
    const int gid = blockIdx.x * blockDim.x + threadIdx.x;
    if (gid < 8 * 32 * 16) {
        const int n = gid >> 9, k = (gid >> 4) & 31, ph = gid & 15;
        const float* w3r = W3 + k * 32;
        const float* h1p = HW1 + (size_t)n * kRH * kPH + ph;
        float s = 0.f;
#pragma unroll
        for (int j = 0; j < 32; ++j) s = fmaf(w3r[j], h1p[j * kPH], s);
        HG[gid] = s;
    }
    if (gid < 128) {
        const int n = gid >> 4, ph = gid & 15;
        const float* h1p = HW1 + (size_t)n * kRH * kPH + ph;
        float s = Hb1[n * kPH + ph];
#pragma unroll
        for (int j = 0; j < 32; ++j) s = fmaf(b3[j], h1p[j * kPH], s);
        Hb1p[gid] = s;
    }
}

// ---------------------------------------------------------------------------
// Pre-kernel 1 (R17, unchanged): frags; head frags source HG.
// ---------------------------------------------------------------------------
__global__ __launch_bounds__(256) void build_wfrags(
    const float* __restrict__ W1, const float* __restrict__ W2,
    const float* __restrict__ W3, const float* __restrict__ HG,
    ushort* __restrict__ WF)
{
    int gid = blockIdx.x * blockDim.x + threadIdx.x;
    if (gid >= kNFrag * 64) return;
    const int q = gid >> 6, l = gid & 63;
    const int lc = l & 31, g = l >> 5;

    const float* src; int k0, col, ldn, p;
    if (q < 12) {
        src = W1; col = lc; ldn = 32; p = 0;
        k0 = (q < 4) ? (16*q + 8*g) : (64 + 8*(q - 4) + 64*g);
    } else if (q < 24) {
        int f = q - 12;
        src = W1; col = lc; ldn = 32; p = 1;
        k0 = (f < 4) ? (16*f + 8*g) : (64 + 8*(f - 4) + 64*g);
    }
    else if (q < 28) { int u2 = q-24; src = W2; k0 = 16*(u2>>1) + 8*g; col = lc; ldn = 32; p = u2&1; }
    else if (q < 32) { int u2 = q-28; src = W3; k0 = 16*(u2>>1) + 8*g; col = lc; ldn = 32; p = u2&1; }
    else {
        int u2 = q-32; int n = u2>>2; int f = (u2>>1)&1; p = u2&1;
        int c128 = n*32 + lc; int head = c128 >> 4, ph = c128 & 15;
        src = HG + (size_t)head * kRH * kPH + ph;
        k0 = 16*f + 8*g; col = 0; ldn = kPH;
    }

    u32 hv[8];
#pragma unroll
    for (int j = 0; j < 8; ++j) {
        float w = src[(size_t)(k0 + j) * ldn + col];
        u32 h = rne_hi(w);
        hv[j] = (p == 0) ? h : rne_hi(w - hi_f32(h));
    }
    FragU fu;
#pragma unroll
    for (int w = 0; w < 4; ++w) fu.w[w] = hv[2*w] | (hv[2*w+1] << 16);
    ((uint4*)WF)[q * 64 + l] = fu.u4;
}

// ---------------------------------------------------------------------------
// Pre-kernel 2 (unchanged): emb -> bf16 HI-ONLY table, 16B records.
// ---------------------------------------------------------------------------
__global__ __launch_bounds__(256) void build_embhi(
    const float* __restrict__ emb, ushort* __restrict__ eh)
{
    int r = blockIdx.x * blockDim.x + threadIdx.x;
    if (r >= kNCate * kVocab) return;
    const float* e = emb + (size_t)r * kEm;
    FragU H;
#pragma unroll
    for (int w = 0; w < 4; ++w)
        H.w[w] = pack2(e[2*w], e[2*w+1]);
    ((uint4*)eh)[r] = H.u4;
}

// ---------------------------------------------------------------------------
// Transition (R16-verified form: manual RNE + shfl_xor).
// ---------------------------------------------------------------------------
__device__ inline void transition(const float* v, int g, FragU* H, FragU* L) {
    u32 hw[8], lw[8];
#pragma unroll
    for (int p = 0; p < 8; ++p) {
        float v0 = v[2*p], v1 = v[2*p+1];
        u32 h0 = rne_hi(v0), h1 = rne_hi(v1);
        hw[p] = h0 | (h1 << 16);
        lw[p] = pack2(v0 - hi_f32(h0), v1 - hi_f32(h1));
    }
#pragma unroll
    for (int f2 = 0; f2 < 2; ++f2) {
        u32 hp[4], lp[4];
#pragma unroll
        for (int p = 0; p < 4; ++p) {
            hp[p] = (u32)__shfl_xor((int)hw[4*f2 + p], 32);
            lp[p] = (u32)__shfl_xor((int)lw[4*f2 + p], 32);
        }
        H[f2].w[0] = g ? hp[2] : hw[4*f2+0];
        H[f2].w[1] = g ? hp[3] : hw[4*f2+1];
        H[f2].w[2] = g ? hw[4*f2+2] : hp[0];
        H[f2].w[3] = g ? hw[4*f2+3] : hp[1];
        L[f2].w[0] = g ? lp[2] : lw[4*f2+0];
        L[f2].w[1] = g ? lp[3] : lw[4*f2+1];
        L[f2].w[2] = g ? lw[4*f2+2] : lp[0];
        L[f2].w[3] = g ? lw[4*f2+3] : lp[1];
    }
}

// ---------------------------------------------------------------------------
// Main kernel (R19): R17 structure, but W1 frags read from GLOBAL (L1)
// instead of LDS. LDS = 32KB xstage + 1.3KB sB -> 4 blocks/CU = 16 waves
// (+33% TLP vs R17's 12). No restrictive VGPR cap.
// ---------------------------------------------------------------------------
__global__ __launch_bounds__(256, 4) void fused_main(
    const float* __restrict__ xc, const int* __restrict__ xcate,
    const int* __restrict__ tptr,
    const ushort* __restrict__ WF,
    const ushort* __restrict__ eh,
    const float* __restrict__ b1, const float* __restrict__ b2,
    const float* __restrict__ Hb1p,
    const float* __restrict__ HW2, const float* __restrict__ Hb2,
    float* __restrict__ out)
{
    __shared__ __align__(16) float sX[4][2048];       // 4 x 8KB x_cont stage
    __shared__ __align__(16) float sB[328];

    const int tid = threadIdx.x;
    const uint4* wf4 = (const uint4*)WF;

    for (int i = tid; i < 328; i += 256) {
        float v;
        if      (i < 32)  v = b1[i];
        else if (i < 64)  v = b2[i - 32];
        else if (i < 192) v = Hb1p[i - 64];
        else if (i < 320) v = HW2[i - 192];
        else              v = Hb2[i - 320];
        sB[i] = v;
    }
    __syncthreads();

    const int wv = tid >> 6, l = tid & 63;
    const int lc = l & 31, g = l >> 5;
    const int rowbase = blockIdx.x * 256 + wv * 64;   // 2 tiles of 32
    char* xb = (char*)&sX[wv][0];
    const uint4* eh4 = (const uint4*)eh;

    auto stage_x = [&](int tbase) {
        const float* xbase = xc + (size_t)tbase * kCont;
#pragma unroll
        for (int i = 0; i < 8; ++i) {
            const int r   = 4*i + (l >> 4);
            const int c4s = (l & 15) ^ (r & 15);
            gload_lds16(xbase + r * kCont + c4s * 4, xb + i * 1024);
        }
    };
    auto load_idx = [&](int tbase, i32x4* iq, int& t_lane) {
        const i32x4* cr4 = (const i32x4*)(xcate + (size_t)(tbase + lc) * kNCate + 8*g);
        iq[0] = cr4[0];
        iq[1] = cr4[1];
        t_lane = tptr[tbase + lc];
    };
    auto gather_emb = [&](const i32x4* iq, uint4* ehv) {
#pragma unroll
        for (int i = 0; i < 8; ++i) {
            const int c   = i + 8*g;
            const int idx = (i < 4) ? iq[0][i] : iq[1][i - 4];
            ehv[i] = eh4[(size_t)(c * kVocab + idx)];
        }
    };
    auto layer1_cont = [&](f32x16& acca, f32x16& accb) {
#pragma unroll
        for (int f = 0; f < 4; ++f) {
            const int c0 = 4*f + 2*g;
            f32x4 va0 = *(const f32x4*)(xb + lc*256 + (((c0)     ^ (lc & 15)) * 16));
            f32x4 va1 = *(const f32x4*)(xb + lc*256 + (((c0 + 1) ^ (lc & 15)) * 16));
            FragU H, L;
#pragma unroll
            for (int w = 0; w < 4; ++w) {
                const f32x4& va = (w < 2) ? va0 : va1;
                const float v0 = va[2*(w & 1)], v1 = va[2*(w & 1) + 1];
                u32 h0 = rne_hi(v0), h1 = rne_hi(v1);
                H.w[w] = h0 | (h1 << 16);
                L.w[w] = pack2(v0 - hi_f32(h0), v1 - hi_f32(h1));
            }
            FragU WH, WL;
            WH.u4 = wf4[f * 64 + l];
            WL.u4 = wf4[(12 + f) * 64 + l];
            f32x16& acc = (f & 1) ? accb : acca;
            acc = mfma16(WH.v, H.v, acc);
            acc = mfma16(WL.v, H.v, acc);
            acc = mfma16(WH.v, L.v, acc);
        }
    };
    auto layer1_emb = [&](const uint4* ehv, f32x16& acca, f32x16& accb) {
#pragma unroll
        for (int i = 0; i < 8; ++i) {
            const int f = 4 + i;
            FragU BH, WH;
            BH.u4 = ehv[i];
            WH.u4 = wf4[f * 64 + l];
            f32x16& acc = (f & 1) ? accb : acca;
            acc = mfma16(WH.v, BH.v, acc);
        }
    };
    auto mid = [&](const f32x16& acca, const f32x16& accb, FragU* aHh, FragU* aHl) {
        float v1v[16];
#pragma unroll
        for (int p = 0; p < 4; ++p) {
            f32x4 bq = *(const f32x4*)&sB[0 + 8*p + 4*g];
#pragma unroll
            for (int m = 0; m < 4; ++m)
                v1v[4*p + m] = fmaxf(acca[4*p + m] + accb[4*p + m] + bq[m], 0.f);
        }
        FragU a2h[2], a2l[2];
        transition(v1v, g, a2h, a2l);

        f32x16 acc2 = zero16();
#pragma unroll
        for (int f2 = 0; f2 < 2; ++f2) {
            FragU WH, WL;
            WH.u4 = wf4[(24 + 2*f2) * 64 + l];
            WL.u4 = wf4[(25 + 2*f2) * 64 + l];
            acc2 = mfma16(WH.v, a2h[f2].v, acc2);
            acc2 = mfma16(WL.v, a2h[f2].v, acc2);
            acc2 = mfma16(WH.v, a2l[f2].v, acc2);
        }
        float v2v[16];
#pragma unroll
        for (int p = 0; p < 4; ++p) {
            f32x4 bq = *(const f32x4*)&sB[32 + 8*p + 4*g];
#pragma unroll
            for (int m = 0; m < 4; ++m)
                v2v[4*p + m] = fmaxf(acc2[4*p + m] + bq[m], 0.f);
        }
        transition(v2v, g, aHh, aHl);
    };
    auto heads_store = [&](const FragU* aHh, const FragU* aHl, int t_lane, int arow) {
        const f32x4 hb1q0 = *(const f32x4*)&sB[64  + t_lane*16 + 4*g];
        const f32x4 hb1q1 = *(const f32x4*)&sB[64  + t_lane*16 + 8 + 4*g];
        const f32x4 hw2q0 = *(const f32x4*)&sB[192 + t_lane*16 + 4*g];
        const f32x4 hw2q1 = *(const f32x4*)&sB[192 + t_lane*16 + 8 + 4*g];

        float ys = 0.f;
#pragma unroll
        for (int n = 0; n < 4; ++n) {
            f32x16 hacc = zero16();
#pragma unroll
            for (int f2 = 0; f2 < 2; ++f2) {
                FragU WH, WL;
                WH.u4 = wf4[(32 + 4*n + 2*f2) * 64 + l];   // HG-hi
                WL.u4 = wf4[(33 + 4*n + 2*f2) * 64 + l];   // HG-lo
                hacc = mfma16(WH.v, aHh[f2].v, hacc);
                hacc = mfma16(WL.v, aHh[f2].v, hacc);
                hacc = mfma16(WH.v, aHl[f2].v, hacc);
            }
            const bool sel = ((t_lane >> 1) == n);
            const bool half = (t_lane & 1);
#pragma unroll
            for (int j = 0; j < 8; ++j) {
                const float bb = (j < 4) ? hb1q0[j] : hb1q1[j - 4];
                const float ww = (j < 4) ? hw2q0[j] : hw2q1[j - 4];
                const float c0 = fmaxf(hacc[j]     + bb, 0.f) * ww;
                const float c1 = fmaxf(hacc[8 + j] + bb, 0.f) * ww;
                const float pick = half ? c1 : c0;
                ys += sel ? pick : 0.f;
            }
        }
        const float ytot = ys + __shfl_xor(ys, 32);
        if (g == 0)
            out[arow] = ytot + sB[320 + t_lane];
    };

    // ---------------- pipelined 2-tile schedule ----------------
    const int tb1 = rowbase, tb2 = rowbase + 32;

    stage_x(tb1);
    i32x4 iq1[2]; int t1;
    load_idx(tb1, iq1, t1);

    fence_vm0();                      // xb(t1) + iq1 + t1 ready

    uint4 ehv1[8];
    gather_emb(iq1, ehv1);            // in flight under cont1

    f32x16 acca = zero16(), accb = zero16();
    layer1_cont(acca, accb);

    fence_lgkm0();                    // xb ds_reads retired -> safe to overwrite
    stage_x(tb2);                     // tile-2 staging under t1 compute
    i32x4 iq2[2]; int t2;
    load_idx(tb2, iq2, t2);

    layer1_emb(ehv1, acca, accb);
    FragU aHh[2], aHl[2];
    mid(acca, accb, aHh, aHl);

    uint4 ehv2[8];
    gather_emb(iq2, ehv2);            // in flight under heads1

    heads_store(aHh, aHl, t1, tb1 + lc);

    fence_vm0();                      // xb(t2) ready

    acca = zero16(); accb = zero16();
    layer1_cont(acca, accb);
    layer1_emb(ehv2, acca, accb);
    mid(acca, accb, aHh, aHl);
    heads_store(aHh, aHl, t2, tb2 + lc);
}

} // namespace

extern "C" void kernel_launch(void* const* d_in, const int* in_sizes, int n_in,
                              void* d_out, int out_size, void* d_ws, size_t ws_size,
                              hipStream_t stream)
{
    const float* x_cont = (const float*)d_in[0];
    const int*   x_cate = (const int*)  d_in[1];
    const int*   t      = (const int*)  d_in[2];
    const float* emb    = (const float*)d_in[3];
    const float* W1     = (const float*)d_in[4];
    const float* b1     = (const float*)d_in[5];
    const float* W2     = (const float*)d_in[6];
    const float* b2     = (const float*)d_in[7];
    const float* W3     = (const float*)d_in[8];
    const float* b3     = (const float*)d_in[9];
    const float* HW1    = (const float*)d_in[10];
    const float* Hb1    = (const float*)d_in[11];
    const float* HW2    = (const float*)d_in[12];
    const float* Hb2    = (const float*)d_in[13];
    float* out = (float*)d_out;

    ushort* WF   = (ushort*)d_ws;
    ushort* eh   = (ushort*)((char*)d_ws + kOffEH);
    float*  HG   = (float*) ((char*)d_ws + kOffHG);
    float*  Hb1p = (float*) ((char*)d_ws + kOffHB);

    hipLaunchKernelGGL(build_hg, dim3(16), dim3(256), 0, stream,
                       W3, HW1, b3, Hb1, HG, Hb1p);
    hipLaunchKernelGGL(build_wfrags, dim3(12), dim3(256), 0, stream,
                       W1, W2, W3, HG, WF);
    hipLaunchKernelGGL(build_embhi, dim3((kNCate*kVocab + 255)/256), dim3(256), 0, stream,
                       emb, eh);

    const int grid = kRows / 256;   // 2048 blocks; 4 waves x 2 tiles x 32 rows
    hipLaunchKernelGGL(fused_main, dim3(grid), dim3(256), 0, stream,
                       x_cont, x_cate, t, WF, eh,
                       b1, b2, Hb1p, HW2, Hb2, out);
}

// Round 21
// 102.679 us; speedup vs baseline: 1.2383x; 1.2383x over previous
//
#include <hip/hip_runtime.h>

namespace {

typedef float  f32x4  __attribute__((ext_vector_type(4)));
typedef float  f32x16 __attribute__((ext_vector_type(16)));
typedef short  bf16x8 __attribute__((ext_vector_type(8)));
typedef int    i32x4  __attribute__((ext_vector_type(4)));
typedef unsigned int u32;

constexpr int kRows  = 524288;
constexpr int kCont  = 64;
constexpr int kNCate = 16;
constexpr int kVocab = 1000;
constexpr int kEm    = 8;
constexpr int kRH    = 32;
constexpr int kPH    = 16;

constexpr int    kNFrag = 48;
constexpr size_t kOffEH = (size_t)kNFrag * 1024;        // 49152
constexpr size_t kOffHG = kOffEH + 256000;              // HG: 8*32*16 f32
constexpr size_t kOffHB = kOffHG + 16384;               // Hb1p: 128 f32

__device__ inline u32 rne_hi(float x) {
    u32 u = __float_as_uint(x);
    return ((u + 0x7fffu + ((u >> 16) & 1u)) >> 16) & 0xffffu;
}
__device__ inline float hi_f32(u32 h) { return __uint_as_float(h << 16); }
__device__ inline u32 pack2(float a, float b) {
    return rne_hi(a) | (rne_hi(b) << 16);
}

union FragU { u32 w[4]; bf16x8 v; uint4 u4; };

__device__ inline f32x16 mfma16(bf16x8 a, bf16x8 b, f32x16 c) {
    return __builtin_amdgcn_mfma_f32_32x32x16_bf16(a, b, c, 0, 0, 0);
}
__device__ inline f32x16 zero16() {
    f32x16 z;
#pragma unroll
    for (int i = 0; i < 16; ++i) z[i] = 0.f;
    return z;
}
__device__ inline void gload_lds16(const void* g, void* l) {
    __builtin_amdgcn_global_load_lds(
        (const __attribute__((address_space(1))) void*)g,
        (__attribute__((address_space(3))) void*)l, 16, 0, 0);
}
__device__ inline void fence_vm0() {
    asm volatile("s_waitcnt vmcnt(0)" ::: "memory");
    __builtin_amdgcn_sched_barrier(0);
}

// ---------------------------------------------------------------------------
// Pre-kernel 0 (unchanged): fold layer 3 into heads.
// ---------------------------------------------------------------------------
__global__ __launch_bounds__(256) void build_hg(
    const float* __restrict__ W3, const float* __restrict__ HW1,
    const float* __restrict__ b3, const float* __restrict__ Hb1,
    float* __restrict__ HG, float* __restrict__ Hb1p)
{
    const int gid = blockIdx.x * blockDim.x + threadIdx.x;
    if (gid < 8 * 32 * 16) {
        const int n = gid >> 9, k = (gid >> 4) & 31, ph = gid & 15;
        const float* w3r = W3 + k * 32;
        const float* h1p = HW1 + (size_t)n * kRH * kPH + ph;
        float s = 0.f;
#pragma unroll
        for (int j = 0; j < 32; ++j) s = fmaf(w3r[j], h1p[j * kPH], s);
        HG[gid] = s;
    }
    if (gid < 128) {
        const int n = gid >> 4, ph = gid & 15;
        const float* h1p = HW1 + (size_t)n * kRH * kPH + ph;
        float s = Hb1[n * kPH + ph];
#pragma unroll
        for (int j = 0; j < 32; ++j) s = fmaf(b3[j], h1p[j * kPH], s);
        Hb1p[gid] = s;
    }
}

// ---------------------------------------------------------------------------
// Pre-kernel 1 (unchanged from R17): frags; head frags source HG.
// ---------------------------------------------------------------------------
__global__ __launch_bounds__(256) void build_wfrags(
    const float* __restrict__ W1, const float* __restrict__ W2,
    const float* __restrict__ W3, const float* __restrict__ HG,
    ushort* __restrict__ WF)
{
    int gid = blockIdx.x * blockDim.x + threadIdx.x;
    if (gid >= kNFrag * 64) return;
    const int q = gid >> 6, l = gid & 63;
    const int lc = l & 31, g = l >> 5;

    const float* src; int k0, col, ldn, p;
    if (q < 12) {
        src = W1; col = lc; ldn = 32; p = 0;
        k0 = (q < 4) ? (16*q + 8*g) : (64 + 8*(q - 4) + 64*g);
    } else if (q < 24) {
        int f = q - 12;
        src = W1; col = lc; ldn = 32; p = 1;
        k0 = (f < 4) ? (16*f + 8*g) : (64 + 8*(f - 4) + 64*g);
    }
    else if (q < 28) { int u2 = q-24; src = W2; k0 = 16*(u2>>1) + 8*g; col = lc; ldn = 32; p = u2&1; }
    else if (q < 32) { int u2 = q-28; src = W3; k0 = 16*(u2>>1) + 8*g; col = lc; ldn = 32; p = u2&1; }
    else {
        int u2 = q-32; int n = u2>>2; int f = (u2>>1)&1; p = u2&1;
        int c128 = n*32 + lc; int head = c128 >> 4, ph = c128 & 15;
        src = HG + (size_t)head * kRH * kPH + ph;
        k0 = 16*f + 8*g; col = 0; ldn = kPH;
    }

    u32 hv[8];
#pragma unroll
    for (int j = 0; j < 8; ++j) {
        float w = src[(size_t)(k0 + j) * ldn + col];
        u32 h = rne_hi(w);
        hv[j] = (p == 0) ? h : rne_hi(w - hi_f32(h));
    }
    FragU fu;
#pragma unroll
    for (int w = 0; w < 4; ++w) fu.w[w] = hv[2*w] | (hv[2*w+1] << 16);
    ((uint4*)WF)[q * 64 + l] = fu.u4;
}

// ---------------------------------------------------------------------------
// Pre-kernel 2 (unchanged): emb -> bf16 HI-ONLY table, 16B records.
// ---------------------------------------------------------------------------
__global__ __launch_bounds__(256) void build_embhi(
    const float* __restrict__ emb, ushort* __restrict__ eh)
{
    int r = blockIdx.x * blockDim.x + threadIdx.x;
    if (r >= kNCate * kVocab) return;
    const float* e = emb + (size_t)r * kEm;
    FragU H;
#pragma unroll
    for (int w = 0; w < 4; ++w)
        H.w[w] = pack2(e[2*w], e[2*w+1]);
    ((uint4*)eh)[r] = H.u4;
}

// ---------------------------------------------------------------------------
// Transition (R16-verified form).
// ---------------------------------------------------------------------------
__device__ inline void transition(const float* v, int g, FragU* H, FragU* L) {
    u32 hw[8], lw[8];
#pragma unroll
    for (int p = 0; p < 8; ++p) {
        float v0 = v[2*p], v1 = v[2*p+1];
        u32 h0 = rne_hi(v0), h1 = rne_hi(v1);
        hw[p] = h0 | (h1 << 16);
        lw[p] = pack2(v0 - hi_f32(h0), v1 - hi_f32(h1));
    }
#pragma unroll
    for (int f2 = 0; f2 < 2; ++f2) {
        u32 hp[4], lp[4];
#pragma unroll
        for (int p = 0; p < 4; ++p) {
            hp[p] = (u32)__shfl_xor((int)hw[4*f2 + p], 32);
            lp[p] = (u32)__shfl_xor((int)lw[4*f2 + p], 32);
        }
        H[f2].w[0] = g ? hp[2] : hw[4*f2+0];
        H[f2].w[1] = g ? hp[3] : hw[4*f2+1];
        H[f2].w[2] = g ? hw[4*f2+2] : hp[0];
        H[f2].w[3] = g ? hw[4*f2+3] : hp[1];
        L[f2].w[0] = g ? lp[2] : lw[4*f2+0];
        L[f2].w[1] = g ? lp[3] : lw[4*f2+1];
        L[f2].w[2] = g ? lw[4*f2+2] : lp[0];
        L[f2].w[3] = g ? lw[4*f2+3] : lp[1];
    }
}

// ---------------------------------------------------------------------------
// Main kernel (R20 resubmit): dual-chain interleave. Tile1 x_cont via
// gload_lds (xb); tile2 x_cont via direct register loads (no false dep,
// no second fence). Both tiles' compute explicitly interleaved per sub-stage
// so every latency has an independent twin. W1 frags in LDS (R19 lesson).
// ---------------------------------------------------------------------------
__global__ __launch_bounds__(256, 2) void fused_main(
    const float* __restrict__ xc, const int* __restrict__ xcate,
    const int* __restrict__ tptr,
    const ushort* __restrict__ WF,
    const ushort* __restrict__ eh,
    const float* __restrict__ b1, const float* __restrict__ b2,
    const float* __restrict__ Hb1p,
    const float* __restrict__ HW2, const float* __restrict__ Hb2,
    float* __restrict__ out)
{
    __shared__ __align__(16) uint4 sW4[16 * 64];      // 16 KB W1 frags
    __shared__ __align__(16) float sX[4][2048];       // 32 KB tile-1 x stage
    __shared__ __align__(16) float sB[328];

    const int tid = threadIdx.x;
    const uint4* wf4 = (const uint4*)WF;

#pragma unroll
    for (int it = 0; it < 4; ++it) {
        const int i = tid + 256 * it;
        sW4[i] = wf4[i];
    }
    for (int i = tid; i < 328; i += 256) {
        float v;
        if      (i < 32)  v = b1[i];
        else if (i < 64)  v = b2[i - 32];
        else if (i < 192) v = Hb1p[i - 64];
        else if (i < 320) v = HW2[i - 192];
        else              v = Hb2[i - 320];
        sB[i] = v;
    }
    __syncthreads();

    const int wv = tid >> 6, l = tid & 63;
    const int lc = l & 31, g = l >> 5;
    const int rowbase = blockIdx.x * 256 + wv * 64;
    const int tb1 = rowbase, tb2 = rowbase + 32;
    char* xb = (char*)&sX[wv][0];
    const uint4* eh4 = (const uint4*)eh;

    // ---- issue ALL input loads up front ----
    {   // tile-1 x_cont -> LDS (coalesced, pre-swizzled source)
        const float* xbase = xc + (size_t)tb1 * kCont;
#pragma unroll
        for (int i = 0; i < 8; ++i) {
            const int r   = 4*i + (l >> 4);
            const int c4s = (l & 15) ^ (r & 15);
            gload_lds16(xbase + r * kCont + c4s * 4, xb + i * 1024);
        }
    }
    i32x4 iq1[2], iq2[2];
    int t1, t2;
    {
        const i32x4* cr1 = (const i32x4*)(xcate + (size_t)(tb1 + lc) * kNCate + 8*g);
        iq1[0] = cr1[0]; iq1[1] = cr1[1];
        const i32x4* cr2 = (const i32x4*)(xcate + (size_t)(tb2 + lc) * kNCate + 8*g);
        iq2[0] = cr2[0]; iq2[1] = cr2[1];
        t1 = tptr[tb1 + lc];
        t2 = tptr[tb2 + lc];
    }
    f32x4 xa2[8];
    {   // tile-2 x_cont -> registers (independent of xb)
        const f32x4* xr4 = (const f32x4*)(xc + (size_t)(tb2 + lc) * kCont);
#pragma unroll
        for (int f = 0; f < 4; ++f) {
            xa2[2*f]   = xr4[4*f + 2*g];
            xa2[2*f+1] = xr4[4*f + 2*g + 1];
        }
    }

    fence_vm0();     // xb + indices + xa2 all resident

    // ---- emb gathers for BOTH tiles fly under cont compute ----
    uint4 ehv1[8], ehv2[8];
#pragma unroll
    for (int i = 0; i < 8; ++i) {
        const int c = i + 8*g;
        const int i1 = (i < 4) ? iq1[0][i] : iq1[1][i - 4];
        const int i2 = (i < 4) ? iq2[0][i] : iq2[1][i - 4];
        ehv1[i] = eh4[(size_t)(c * kVocab + i1)];
        ehv2[i] = eh4[(size_t)(c * kVocab + i2)];
    }

    // ---- layer 1 cont: interleaved, 4 independent acc chains ----
    f32x16 A1a = zero16(), A1b = zero16(), A2a = zero16(), A2b = zero16();
#pragma unroll
    for (int f = 0; f < 4; ++f) {
        FragU WH, WL;
        WH.u4 = sW4[f * 64 + l];
        WL.u4 = sW4[(12 + f) * 64 + l];
        // tile 1 (from LDS)
        {
            const int c0 = 4*f + 2*g;
            f32x4 va0 = *(const f32x4*)(xb + lc*256 + (((c0)     ^ (lc & 15)) * 16));
            f32x4 va1 = *(const f32x4*)(xb + lc*256 + (((c0 + 1) ^ (lc & 15)) * 16));
            FragU H, L;
#pragma unroll
            for (int w = 0; w < 4; ++w) {
                const f32x4& va = (w < 2) ? va0 : va1;
                const float v0 = va[2*(w & 1)], v1 = va[2*(w & 1) + 1];
                u32 h0 = rne_hi(v0), h1 = rne_hi(v1);
                H.w[w] = h0 | (h1 << 16);
                L.w[w] = pack2(v0 - hi_f32(h0), v1 - hi_f32(h1));
            }
            f32x16& acc = (f & 1) ? A1b : A1a;
            acc = mfma16(WH.v, H.v, acc);
            acc = mfma16(WL.v, H.v, acc);
            acc = mfma16(WH.v, L.v, acc);
        }
        // tile 2 (from registers)
        {
            f32x4 va0 = xa2[2*f], va1 = xa2[2*f+1];
            FragU H, L;
#pragma unroll
            for (int w = 0; w < 4; ++w) {
                const f32x4& va = (w < 2) ? va0 : va1;
                const float v0 = va[2*(w & 1)], v1 = va[2*(w & 1) + 1];
                u32 h0 = rne_hi(v0), h1 = rne_hi(v1);
                H.w[w] = h0 | (h1 << 16);
                L.w[w] = pack2(v0 - hi_f32(h0), v1 - hi_f32(h1));
            }
            f32x16& acc = (f & 1) ? A2b : A2a;
            acc = mfma16(WH.v, H.v, acc);
            acc = mfma16(WL.v, H.v, acc);
            acc = mfma16(WH.v, L.v, acc);
        }
    }

    // ---- layer 1 emb: interleaved ----
#pragma unroll
    for (int i = 0; i < 8; ++i) {
        const int f = 4 + i;
        FragU WH;
        WH.u4 = sW4[f * 64 + l];
        FragU B1, B2;
        B1.u4 = ehv1[i]; B2.u4 = ehv2[i];
        f32x16& a1 = (f & 1) ? A1b : A1a;
        f32x16& a2 = (f & 1) ? A2b : A2a;
        a1 = mfma16(WH.v, B1.v, a1);
        a2 = mfma16(WH.v, B2.v, a2);
    }

    // ---- mid: bias+relu / transition / layer-2 / bias+relu / transition ----
    float v1v1[16], v1v2[16];
#pragma unroll
    for (int p = 0; p < 4; ++p) {
        f32x4 bq = *(const f32x4*)&sB[0 + 8*p + 4*g];
#pragma unroll
        for (int m = 0; m < 4; ++m) {
            v1v1[4*p + m] = fmaxf(A1a[4*p + m] + A1b[4*p + m] + bq[m], 0.f);
            v1v2[4*p + m] = fmaxf(A2a[4*p + m] + A2b[4*p + m] + bq[m], 0.f);
        }
    }
    FragU a2h1[2], a2l1[2], a2h2[2], a2l2[2];
    transition(v1v1, g, a2h1, a2l1);
    transition(v1v2, g, a2h2, a2l2);

    f32x16 C1 = zero16(), C2 = zero16();
#pragma unroll
    for (int f2 = 0; f2 < 2; ++f2) {
        FragU WH, WL;
        WH.u4 = wf4[(24 + 2*f2) * 64 + l];
        WL.u4 = wf4[(25 + 2*f2) * 64 + l];
        C1 = mfma16(WH.v, a2h1[f2].v, C1);
        C2 = mfma16(WH.v, a2h2[f2].v, C2);
        C1 = mfma16(WL.v, a2h1[f2].v, C1);
        C2 = mfma16(WL.v, a2h2[f2].v, C2);
        C1 = mfma16(WH.v, a2l1[f2].v, C1);
        C2 = mfma16(WH.v, a2l2[f2].v, C2);
    }
    float v2v1[16], v2v2[16];
#pragma unroll
    for (int p = 0; p < 4; ++p) {
        f32x4 bq = *(const f32x4*)&sB[32 + 8*p + 4*g];
#pragma unroll
        for (int m = 0; m < 4; ++m) {
            v2v1[4*p + m] = fmaxf(C1[4*p + m] + bq[m], 0.f);
            v2v2[4*p + m] = fmaxf(C2[4*p + m] + bq[m], 0.f);
        }
    }
    FragU aHh1[2], aHl1[2], aHh2[2], aHl2[2];
    transition(v2v1, g, aHh1, aHl1);
    transition(v2v2, g, aHh2, aHl2);

    // ---- heads: interleaved n-loop ----
    const f32x4 hb1q0_1 = *(const f32x4*)&sB[64  + t1*16 + 4*g];
    const f32x4 hb1q1_1 = *(const f32x4*)&sB[64  + t1*16 + 8 + 4*g];
    const f32x4 hw2q0_1 = *(const f32x4*)&sB[192 + t1*16 + 4*g];
    const f32x4 hw2q1_1 = *(const f32x4*)&sB[192 + t1*16 + 8 + 4*g];
    const f32x4 hb1q0_2 = *(const f32x4*)&sB[64  + t2*16 + 4*g];
    const f32x4 hb1q1_2 = *(const f32x4*)&sB[64  + t2*16 + 8 + 4*g];
    const f32x4 hw2q0_2 = *(const f32x4*)&sB[192 + t2*16 + 4*g];
    const f32x4 hw2q1_2 = *(const f32x4*)&sB[192 + t2*16 + 8 + 4*g];

    float ys1 = 0.f, ys2 = 0.f;
    const bool half1 = (t1 & 1), half2 = (t2 & 1);
#pragma unroll
    for (int n = 0; n < 4; ++n) {
        FragU WH0, WL0, WH1, WL1;
        WH0.u4 = wf4[(32 + 4*n + 0) * 64 + l];
        WL0.u4 = wf4[(33 + 4*n + 0) * 64 + l];
        WH1.u4 = wf4[(32 + 4*n + 2) * 64 + l];
        WL1.u4 = wf4[(33 + 4*n + 2) * 64 + l];

        f32x16 h1acc = zero16(), h2acc = zero16();
        h1acc = mfma16(WH0.v, aHh1[0].v, h1acc);
        h2acc = mfma16(WH0.v, aHh2[0].v, h2acc);
        h1acc = mfma16(WL0.v, aHh1[0].v, h1acc);
        h2acc = mfma16(WL0.v, aHh2[0].v, h2acc);
        h1acc = mfma16(WH0.v, aHl1[0].v, h1acc);
        h2acc = mfma16(WH0.v, aHl2[0].v, h2acc);
        h1acc = mfma16(WH1.v, aHh1[1].v, h1acc);
        h2acc = mfma16(WH1.v, aHh2[1].v, h2acc);
        h1acc = mfma16(WL1.v, aHh1[1].v, h1acc);
        h2acc = mfma16(WL1.v, aHh2[1].v, h2acc);
        h1acc = mfma16(WH1.v, aHl1[1].v, h1acc);
        h2acc = mfma16(WH1.v, aHl2[1].v, h2acc);

        const bool sel1 = ((t1 >> 1) == n);
        const bool sel2 = ((t2 >> 1) == n);
#pragma unroll
        for (int j = 0; j < 8; ++j) {
            const float bb1 = (j < 4) ? hb1q0_1[j] : hb1q1_1[j - 4];
            const float ww1 = (j < 4) ? hw2q0_1[j] : hw2q1_1[j - 4];
            const float hv1 = half1 ? h1acc[8 + j] : h1acc[j];
            ys1 += sel1 ? fmaxf(hv1 + bb1, 0.f) * ww1 : 0.f;
            const float bb2 = (j < 4) ? hb1q0_2[j] : hb1q1_2[j - 4];
            const float ww2 = (j < 4) ? hw2q0_2[j] : hw2q1_2[j - 4];
            const float hv2 = half2 ? h2acc[8 + j] : h2acc[j];
            ys2 += sel2 ? fmaxf(hv2 + bb2, 0.f) * ww2 : 0.f;
        }
    }

    const float yt1 = ys1 + __shfl_xor(ys1, 32);
    const float yt2 = ys2 + __shfl_xor(ys2, 32);
    if (g == 0) {
        out[tb1 + lc] = yt1 + sB[320 + t1];
        out[tb2 + lc] = yt2 + sB[320 + t2];
    }
}

} // namespace

extern "C" void kernel_launch(void* const* d_in, const int* in_sizes, int n_in,
                              void* d_out, int out_size, void* d_ws, size_t ws_size,
                              hipStream_t stream)
{
    const float* x_cont = (const float*)d_in[0];
    const int*   x_cate = (const int*)  d_in[1];
    const int*   t      = (const int*)  d_in[2];
    const float* emb    = (const float*)d_in[3];
    const float* W1     = (const float*)d_in[4];
    const float* b1     = (const float*)d_in[5];
    const float* W2     = (const float*)d_in[6];
    const float* b2     = (const float*)d_in[7];
    const float* W3     = (const float*)d_in[8];
    const float* b3     = (const float*)d_in[9];
    const float* HW1    = (const float*)d_in[10];
    const float* Hb1    = (const float*)d_in[11];
    const float* HW2    = (const float*)d_in[12];
    const float* Hb2    = (const float*)d_in[13];
    float* out = (float*)d_out;

    ushort* WF   = (ushort*)d_ws;
    ushort* eh   = (ushort*)((char*)d_ws + kOffEH);
    float*  HG   = (float*) ((char*)d_ws + kOffHG);
    float*  Hb1p = (float*) ((char*)d_ws + kOffHB);

    hipLaunchKernelGGL(build_hg, dim3(16), dim3(256), 0, stream,
                       W3, HW1, b3, Hb1, HG, Hb1p);
    hipLaunchKernelGGL(build_wfrags, dim3(12), dim3(256), 0, stream,
                       W1, W2, W3, HG, WF);
    hipLaunchKernelGGL(build_embhi, dim3((kNCate*kVocab + 255)/256), dim3(256), 0, stream,
                       emb, eh);

    const int grid = kRows / 256;   // 2048 blocks; 4 waves x 2 tiles x 32 rows
    hipLaunchKernelGGL(fused_main, dim3(grid), dim3(256), 0, stream,
                       x_cont, x_cate, t, WF, eh,
                       b1, b2, Hb1p, HW2, Hb2, out);
}

// Round 22
// 100.406 us; speedup vs baseline: 1.2664x; 1.0226x over previous
//
#include <hip/hip_runtime.h>

namespace {

typedef float  f32x4  __attribute__((ext_vector_type(4)));
typedef float  f32x16 __attribute__((ext_vector_type(16)));
typedef short  bf16x8 __attribute__((ext_vector_type(8)));
typedef int    i32x4  __attribute__((ext_vector_type(4)));
typedef unsigned int u32;

constexpr int kRows  = 524288;
constexpr int kCont  = 64;
constexpr int kNCate = 16;
constexpr int kVocab = 1000;
constexpr int kEm    = 8;
constexpr int kRH    = 32;
constexpr int kPH    = 16;

constexpr int    kNFrag = 48;
constexpr size_t kOffEH = (size_t)kNFrag * 1024;        // 49152
constexpr size_t kOffHG = kOffEH + 256000;              // HG: 8*32*16 f32
constexpr size_t kOffHB = kOffHG + 16384;               // Hb1p: 128 f32

__device__ inline u32 rne_hi(float x) {
    u32 u = __float_as_uint(x);
    return ((u + 0x7fffu + ((u >> 16) & 1u)) >> 16) & 0xffffu;
}
__device__ inline float hi_f32(u32 h) { return __uint_as_float(h << 16); }
__device__ inline u32 pack2(float a, float b) {
    return rne_hi(a) | (rne_hi(b) << 16);
}

union FragU { u32 w[4]; bf16x8 v; uint4 u4; };

__device__ inline f32x16 mfma16(bf16x8 a, bf16x8 b, f32x16 c) {
    return __builtin_amdgcn_mfma_f32_32x32x16_bf16(a, b, c, 0, 0, 0);
}
__device__ inline f32x16 zero16() {
    f32x16 z;
#pragma unroll
    for (int i = 0; i < 16; ++i) z[i] = 0.f;
    return z;
}
__device__ inline void gload_lds16(const void* g, void* l) {
    __builtin_amdgcn_global_load_lds(
        (const __attribute__((address_space(1))) void*)g,
        (__attribute__((address_space(3))) void*)l, 16, 0, 0);
}
__device__ inline void fence_vm0() {
    asm volatile("s_waitcnt vmcnt(0)" ::: "memory");
    __builtin_amdgcn_sched_barrier(0);
}

// ---------------------------------------------------------------------------
// Pre-kernel 0 (unchanged): fold layer 3 into heads.
// ---------------------------------------------------------------------------
__global__ __launch_bounds__(256) void build_hg(
    const float* __restrict__ W3, const float* __restrict__ HW1,
    const float* __restrict__ b3, const float* __restrict__ Hb1,
    float* __restrict__ HG, float* __restrict__ Hb1p)
{
    const int gid = blockIdx.x * blockDim.x + threadIdx.x;
    if (gid < 8 * 32 * 16) {
        const int n = gid >> 9, k = (gid >> 4) & 31, ph = gid & 15;
        const float* w3r = W3 + k * 32;
        const float* h1p = HW1 + (size_t)n * kRH * kPH + ph;
        float s = 0.f;
#pragma unroll
        for (int j = 0; j < 32; ++j) s = fmaf(w3r[j], h1p[j * kPH], s);
        HG[gid] = s;
    }
    if (gid < 128) {
        const int n = gid >> 4, ph = gid & 15;
        const float* h1p = HW1 + (size_t)n * kRH * kPH + ph;
        float s = Hb1[n * kPH + ph];
#pragma unroll
        for (int j = 0; j < 32; ++j) s = fmaf(b3[j], h1p[j * kPH], s);
        Hb1p[gid] = s;
    }
}

// ---------------------------------------------------------------------------
// Pre-kernel 1 (unchanged from R17): frags; head frags source HG.
// ---------------------------------------------------------------------------
__global__ __launch_bounds__(256) void build_wfrags(
    const float* __restrict__ W1, const float* __restrict__ W2,
    const float* __restrict__ W3, const float* __restrict__ HG,
    ushort* __restrict__ WF)
{
    int gid = blockIdx.x * blockDim.x + threadIdx.x;
    if (gid >= kNFrag * 64) return;
    const int q = gid >> 6, l = gid & 63;
    const int lc = l & 31, g = l >> 5;

    const float* src; int k0, col, ldn, p;
    if (q < 12) {
        src = W1; col = lc; ldn = 32; p = 0;
        k0 = (q < 4) ? (16*q + 8*g) : (64 + 8*(q - 4) + 64*g);
    } else if (q < 24) {
        int f = q - 12;
        src = W1; col = lc; ldn = 32; p = 1;
        k0 = (f < 4) ? (16*f + 8*g) : (64 + 8*(f - 4) + 64*g);
    }
    else if (q < 28) { int u2 = q-24; src = W2; k0 = 16*(u2>>1) + 8*g; col = lc; ldn = 32; p = u2&1; }
    else if (q < 32) { int u2 = q-28; src = W3; k0 = 16*(u2>>1) + 8*g; col = lc; ldn = 32; p = u2&1; }
    else {
        int u2 = q-32; int n = u2>>2; int f = (u2>>1)&1; p = u2&1;
        int c128 = n*32 + lc; int head = c128 >> 4, ph = c128 & 15;
        src = HG + (size_t)head * kRH * kPH + ph;
        k0 = 16*f + 8*g; col = 0; ldn = kPH;
    }

    u32 hv[8];
#pragma unroll
    for (int j = 0; j < 8; ++j) {
        float w = src[(size_t)(k0 + j) * ldn + col];
        u32 h = rne_hi(w);
        hv[j] = (p == 0) ? h : rne_hi(w - hi_f32(h));
    }
    FragU fu;
#pragma unroll
    for (int w = 0; w < 4; ++w) fu.w[w] = hv[2*w] | (hv[2*w+1] << 16);
    ((uint4*)WF)[q * 64 + l] = fu.u4;
}

// ---------------------------------------------------------------------------
// Pre-kernel 2 (unchanged): emb -> bf16 HI-ONLY table, 16B records.
// ---------------------------------------------------------------------------
__global__ __launch_bounds__(256) void build_embhi(
    const float* __restrict__ emb, ushort* __restrict__ eh)
{
    int r = blockIdx.x * blockDim.x + threadIdx.x;
    if (r >= kNCate * kVocab) return;
    const float* e = emb + (size_t)r * kEm;
    FragU H;
#pragma unroll
    for (int w = 0; w < 4; ++w)
        H.w[w] = pack2(e[2*w], e[2*w+1]);
    ((uint4*)eh)[r] = H.u4;
}

// ---------------------------------------------------------------------------
// Transition (R16-verified form).
// ---------------------------------------------------------------------------
__device__ inline void transition(const float* v, int g, FragU* H, FragU* L) {
    u32 hw[8], lw[8];
#pragma unroll
    for (int p = 0; p < 8; ++p) {
        float v0 = v[2*p], v1 = v[2*p+1];
        u32 h0 = rne_hi(v0), h1 = rne_hi(v1);
        hw[p] = h0 | (h1 << 16);
        lw[p] = pack2(v0 - hi_f32(h0), v1 - hi_f32(h1));
    }
#pragma unroll
    for (int f2 = 0; f2 < 2; ++f2) {
        u32 hp[4], lp[4];
#pragma unroll
        for (int p = 0; p < 4; ++p) {
            hp[p] = (u32)__shfl_xor((int)hw[4*f2 + p], 32);
            lp[p] = (u32)__shfl_xor((int)lw[4*f2 + p], 32);
        }
        H[f2].w[0] = g ? hp[2] : hw[4*f2+0];
        H[f2].w[1] = g ? hp[3] : hw[4*f2+1];
        H[f2].w[2] = g ? hw[4*f2+2] : hp[0];
        H[f2].w[3] = g ? hw[4*f2+3] : hp[1];
        L[f2].w[0] = g ? lp[2] : lw[4*f2+0];
        L[f2].w[1] = g ? lp[3] : lw[4*f2+1];
        L[f2].w[2] = g ? lw[4*f2+2] : lp[0];
        L[f2].w[3] = g ? lw[4*f2+3] : lp[1];
    }
}

// ---------------------------------------------------------------------------
// Main kernel (R22 = R20 structure, launch_bounds (256,3)): dual-chain
// interleave at FULL occupancy (3 blocks/CU, 12 waves). Tile1 x_cont via
// gload_lds (xb); tile2 x_cont via registers. VGPR measured 96 < 170 cap.
// ---------------------------------------------------------------------------
__global__ __launch_bounds__(256, 3) void fused_main(
    const float* __restrict__ xc, const int* __restrict__ xcate,
    const int* __restrict__ tptr,
    const ushort* __restrict__ WF,
    const ushort* __restrict__ eh,
    const float* __restrict__ b1, const float* __restrict__ b2,
    const float* __restrict__ Hb1p,
    const float* __restrict__ HW2, const float* __restrict__ Hb2,
    float* __restrict__ out)
{
    __shared__ __align__(16) uint4 sW4[16 * 64];      // 16 KB W1 frags
    __shared__ __align__(16) float sX[4][2048];       // 32 KB tile-1 x stage
    __shared__ __align__(16) float sB[328];

    const int tid = threadIdx.x;
    const uint4* wf4 = (const uint4*)WF;

#pragma unroll
    for (int it = 0; it < 4; ++it) {
        const int i = tid + 256 * it;
        sW4[i] = wf4[i];
    }
    for (int i = tid; i < 328; i += 256) {
        float v;
        if      (i < 32)  v = b1[i];
        else if (i < 64)  v = b2[i - 32];
        else if (i < 192) v = Hb1p[i - 64];
        else if (i < 320) v = HW2[i - 192];
        else              v = Hb2[i - 320];
        sB[i] = v;
    }
    __syncthreads();

    const int wv = tid >> 6, l = tid & 63;
    const int lc = l & 31, g = l >> 5;
    const int rowbase = blockIdx.x * 256 + wv * 64;
    const int tb1 = rowbase, tb2 = rowbase + 32;
    char* xb = (char*)&sX[wv][0];
    const uint4* eh4 = (const uint4*)eh;

    // ---- issue ALL input loads up front ----
    {   // tile-1 x_cont -> LDS (coalesced, pre-swizzled source)
        const float* xbase = xc + (size_t)tb1 * kCont;
#pragma unroll
        for (int i = 0; i < 8; ++i) {
            const int r   = 4*i + (l >> 4);
            const int c4s = (l & 15) ^ (r & 15);
            gload_lds16(xbase + r * kCont + c4s * 4, xb + i * 1024);
        }
    }
    i32x4 iq1[2], iq2[2];
    int t1, t2;
    {
        const i32x4* cr1 = (const i32x4*)(xcate + (size_t)(tb1 + lc) * kNCate + 8*g);
        iq1[0] = cr1[0]; iq1[1] = cr1[1];
        const i32x4* cr2 = (const i32x4*)(xcate + (size_t)(tb2 + lc) * kNCate + 8*g);
        iq2[0] = cr2[0]; iq2[1] = cr2[1];
        t1 = tptr[tb1 + lc];
        t2 = tptr[tb2 + lc];
    }
    f32x4 xa2[8];
    {   // tile-2 x_cont -> registers (independent of xb)
        const f32x4* xr4 = (const f32x4*)(xc + (size_t)(tb2 + lc) * kCont);
#pragma unroll
        for (int f = 0; f < 4; ++f) {
            xa2[2*f]   = xr4[4*f + 2*g];
            xa2[2*f+1] = xr4[4*f + 2*g + 1];
        }
    }

    fence_vm0();     // xb + indices + xa2 all resident

    // ---- emb gathers for BOTH tiles fly under cont compute ----
    uint4 ehv1[8], ehv2[8];
#pragma unroll
    for (int i = 0; i < 8; ++i) {
        const int c = i + 8*g;
        const int i1 = (i < 4) ? iq1[0][i] : iq1[1][i - 4];
        const int i2 = (i < 4) ? iq2[0][i] : iq2[1][i - 4];
        ehv1[i] = eh4[(size_t)(c * kVocab + i1)];
        ehv2[i] = eh4[(size_t)(c * kVocab + i2)];
    }

    // ---- layer 1 cont: interleaved, 4 independent acc chains ----
    f32x16 A1a = zero16(), A1b = zero16(), A2a = zero16(), A2b = zero16();
#pragma unroll
    for (int f = 0; f < 4; ++f) {
        FragU WH, WL;
        WH.u4 = sW4[f * 64 + l];
        WL.u4 = sW4[(12 + f) * 64 + l];
        // tile 1 (from LDS)
        {
            const int c0 = 4*f + 2*g;
            f32x4 va0 = *(const f32x4*)(xb + lc*256 + (((c0)     ^ (lc & 15)) * 16));
            f32x4 va1 = *(const f32x4*)(xb + lc*256 + (((c0 + 1) ^ (lc & 15)) * 16));
            FragU H, L;
#pragma unroll
            for (int w = 0; w < 4; ++w) {
                const f32x4& va = (w < 2) ? va0 : va1;
                const float v0 = va[2*(w & 1)], v1 = va[2*(w & 1) + 1];
                u32 h0 = rne_hi(v0), h1 = rne_hi(v1);
                H.w[w] = h0 | (h1 << 16);
                L.w[w] = pack2(v0 - hi_f32(h0), v1 - hi_f32(h1));
            }
            f32x16& acc = (f & 1) ? A1b : A1a;
            acc = mfma16(WH.v, H.v, acc);
            acc = mfma16(WL.v, H.v, acc);
            acc = mfma16(WH.v, L.v, acc);
        }
        // tile 2 (from registers)
        {
            f32x4 va0 = xa2[2*f], va1 = xa2[2*f+1];
            FragU H, L;
#pragma unroll
            for (int w = 0; w < 4; ++w) {
                const f32x4& va = (w < 2) ? va0 : va1;
                const float v0 = va[2*(w & 1)], v1 = va[2*(w & 1) + 1];
                u32 h0 = rne_hi(v0), h1 = rne_hi(v1);
                H.w[w] = h0 | (h1 << 16);
                L.w[w] = pack2(v0 - hi_f32(h0), v1 - hi_f32(h1));
            }
            f32x16& acc = (f & 1) ? A2b : A2a;
            acc = mfma16(WH.v, H.v, acc);
            acc = mfma16(WL.v, H.v, acc);
            acc = mfma16(WH.v, L.v, acc);
        }
    }

    // ---- layer 1 emb: interleaved ----
#pragma unroll
    for (int i = 0; i < 8; ++i) {
        const int f = 4 + i;
        FragU WH;
        WH.u4 = sW4[f * 64 + l];
        FragU B1, B2;
        B1.u4 = ehv1[i]; B2.u4 = ehv2[i];
        f32x16& a1 = (f & 1) ? A1b : A1a;
        f32x16& a2 = (f & 1) ? A2b : A2a;
        a1 = mfma16(WH.v, B1.v, a1);
        a2 = mfma16(WH.v, B2.v, a2);
    }

    // ---- mid: bias+relu / transition / layer-2 / bias+relu / transition ----
    float v1v1[16], v1v2[16];
#pragma unroll
    for (int p = 0; p < 4; ++p) {
        f32x4 bq = *(const f32x4*)&sB[0 + 8*p + 4*g];
#pragma unroll
        for (int m = 0; m < 4; ++m) {
            v1v1[4*p + m] = fmaxf(A1a[4*p + m] + A1b[4*p + m] + bq[m], 0.f);
            v1v2[4*p + m] = fmaxf(A2a[4*p + m] + A2b[4*p + m] + bq[m], 0.f);
        }
    }
    FragU a2h1[2], a2l1[2], a2h2[2], a2l2[2];
    transition(v1v1, g, a2h1, a2l1);
    transition(v1v2, g, a2h2, a2l2);

    f32x16 C1 = zero16(), C2 = zero16();
#pragma unroll
    for (int f2 = 0; f2 < 2; ++f2) {
        FragU WH, WL;
        WH.u4 = wf4[(24 + 2*f2) * 64 + l];
        WL.u4 = wf4[(25 + 2*f2) * 64 + l];
        C1 = mfma16(WH.v, a2h1[f2].v, C1);
        C2 = mfma16(WH.v, a2h2[f2].v, C2);
        C1 = mfma16(WL.v, a2h1[f2].v, C1);
        C2 = mfma16(WL.v, a2h2[f2].v, C2);
        C1 = mfma16(WH.v, a2l1[f2].v, C1);
        C2 = mfma16(WH.v, a2l2[f2].v, C2);
    }
    float v2v1[16], v2v2[16];
#pragma unroll
    for (int p = 0; p < 4; ++p) {
        f32x4 bq = *(const f32x4*)&sB[32 + 8*p + 4*g];
#pragma unroll
        for (int m = 0; m < 4; ++m) {
            v2v1[4*p + m] = fmaxf(C1[4*p + m] + bq[m], 0.f);
            v2v2[4*p + m] = fmaxf(C2[4*p + m] + bq[m], 0.f);
        }
    }
    FragU aHh1[2], aHl1[2], aHh2[2], aHl2[2];
    transition(v2v1, g, aHh1, aHl1);
    transition(v2v2, g, aHh2, aHl2);

    // ---- heads: interleaved n-loop ----
    const f32x4 hb1q0_1 = *(const f32x4*)&sB[64  + t1*16 + 4*g];
    const f32x4 hb1q1_1 = *(const f32x4*)&sB[64  + t1*16 + 8 + 4*g];
    const f32x4 hw2q0_1 = *(const f32x4*)&sB[192 + t1*16 + 4*g];
    const f32x4 hw2q1_1 = *(const f32x4*)&sB[192 + t1*16 + 8 + 4*g];
    const f32x4 hb1q0_2 = *(const f32x4*)&sB[64  + t2*16 + 4*g];
    const f32x4 hb1q1_2 = *(const f32x4*)&sB[64  + t2*16 + 8 + 4*g];
    const f32x4 hw2q0_2 = *(const f32x4*)&sB[192 + t2*16 + 4*g];
    const f32x4 hw2q1_2 = *(const f32x4*)&sB[192 + t2*16 + 8 + 4*g];

    float ys1 = 0.f, ys2 = 0.f;
    const bool half1 = (t1 & 1), half2 = (t2 & 1);
#pragma unroll
    for (int n = 0; n < 4; ++n) {
        FragU WH0, WL0, WH1, WL1;
        WH0.u4 = wf4[(32 + 4*n + 0) * 64 + l];
        WL0.u4 = wf4[(33 + 4*n + 0) * 64 + l];
        WH1.u4 = wf4[(32 + 4*n + 2) * 64 + l];
        WL1.u4 = wf4[(33 + 4*n + 2) * 64 + l];

        f32x16 h1acc = zero16(), h2acc = zero16();
        h1acc = mfma16(WH0.v, aHh1[0].v, h1acc);
        h2acc = mfma16(WH0.v, aHh2[0].v, h2acc);
        h1acc = mfma16(WL0.v, aHh1[0].v, h1acc);
        h2acc = mfma16(WL0.v, aHh2[0].v, h2acc);
        h1acc = mfma16(WH0.v, aHl1[0].v, h1acc);
        h2acc = mfma16(WH0.v, aHl2[0].v, h2acc);
        h1acc = mfma16(WH1.v, aHh1[1].v, h1acc);
        h2acc = mfma16(WH1.v, aHh2[1].v, h2acc);
        h1acc = mfma16(WL1.v, aHh1[1].v, h1acc);
        h2acc = mfma16(WL1.v, aHh2[1].v, h2acc);
        h1acc = mfma16(WH1.v, aHl1[1].v, h1acc);
        h2acc = mfma16(WH1.v, aHl2[1].v, h2acc);

        const bool sel1 = ((t1 >> 1) == n);
        const bool sel2 = ((t2 >> 1) == n);
#pragma unroll
        for (int j = 0; j < 8; ++j) {
            const float bb1 = (j < 4) ? hb1q0_1[j] : hb1q1_1[j - 4];
            const float ww1 = (j < 4) ? hw2q0_1[j] : hw2q1_1[j - 4];
            const float hv1 = half1 ? h1acc[8 + j] : h1acc[j];
            ys1 += sel1 ? fmaxf(hv1 + bb1, 0.f) * ww1 : 0.f;
            const float bb2 = (j < 4) ? hb1q0_2[j] : hb1q1_2[j - 4];
            const float ww2 = (j < 4) ? hw2q0_2[j] : hw2q1_2[j - 4];
            const float hv2 = half2 ? h2acc[8 + j] : h2acc[j];
            ys2 += sel2 ? fmaxf(hv2 + bb2, 0.f) * ww2 : 0.f;
        }
    }

    const float yt1 = ys1 + __shfl_xor(ys1, 32);
    const float yt2 = ys2 + __shfl_xor(ys2, 32);
    if (g == 0) {
        out[tb1 + lc] = yt1 + sB[320 + t1];
        out[tb2 + lc] = yt2 + sB[320 + t2];
    }
}

} // namespace

extern "C" void kernel_launch(void* const* d_in, const int* in_sizes, int n_in,
                              void* d_out, int out_size, void* d_ws, size_t ws_size,
                              hipStream_t stream)
{
    const float* x_cont = (const float*)d_in[0];
    const int*   x_cate = (const int*)  d_in[1];
    const int*   t      = (const int*)  d_in[2];
    const float* emb    = (const float*)d_in[3];
    const float* W1     = (const float*)d_in[4];
    const float* b1     = (const float*)d_in[5];
    const float* W2     = (const float*)d_in[6];
    const float* b2     = (const float*)d_in[7];
    const float* W3     = (const float*)d_in[8];
    const float* b3     = (const float*)d_in[9];
    const float* HW1    = (const float*)d_in[10];
    const float* Hb1    = (const float*)d_in[11];
    const float* HW2    = (const float*)d_in[12];
    const float* Hb2    = (const float*)d_in[13];
    float* out = (float*)d_out;

    ushort* WF   = (ushort*)d_ws;
    ushort* eh   = (ushort*)((char*)d_ws + kOffEH);
    float*  HG   = (float*) ((char*)d_ws + kOffHG);
    float*  Hb1p = (float*) ((char*)d_ws + kOffHB);

    hipLaunchKernelGGL(build_hg, dim3(16), dim3(256), 0, stream,
                       W3, HW1, b3, Hb1, HG, Hb1p);
    hipLaunchKernelGGL(build_wfrags, dim3(12), dim3(256), 0, stream,
                       W1, W2, W3, HG, WF);
    hipLaunchKernelGGL(build_embhi, dim3((kNCate*kVocab + 255)/256), dim3(256), 0, stream,
                       emb, eh);

    const int grid = kRows / 256;   // 2048 blocks; 4 waves x 2 tiles x 32 rows
    hipLaunchKernelGGL(fused_main, dim3(grid), dim3(256), 0, stream,
                       x_cont, x_cate, t, WF, eh,
                       b1, b2, Hb1p, HW2, Hb2, out);
}

// Round 23
// 75.073 us; speedup vs baseline: 1.6937x; 1.3374x over previous
//
#include <hip/hip_runtime.h>

namespace {

typedef float  f32x4  __attribute__((ext_vector_type(4)));
typedef float  f32x16 __attribute__((ext_vector_type(16)));
typedef short  bf16x8 __attribute__((ext_vector_type(8)));
typedef int    i32x4  __attribute__((ext_vector_type(4)));
typedef unsigned int u32;

constexpr int kRows  = 524288;
constexpr int kCont  = 64;
constexpr int kNCate = 16;
constexpr int kVocab = 1000;
constexpr int kEm    = 8;
constexpr int kRH    = 32;
constexpr int kPH    = 16;

constexpr int    kNFrag = 48;
constexpr size_t kOffEH = (size_t)kNFrag * 1024;    // 49152; EH = 16000 x 16B

__device__ inline u32 rne_hi(float x) {
    u32 u = __float_as_uint(x);
    return ((u + 0x7fffu + ((u >> 16) & 1u)) >> 16) & 0xffffu;
}
__device__ inline float hi_f32(u32 h) { return __uint_as_float(h << 16); }
__device__ inline u32 pack2(float a, float b) {
    return rne_hi(a) | (rne_hi(b) << 16);
}

union FragU { u32 w[4]; bf16x8 v; uint4 u4; };

__device__ inline f32x16 mfma16(bf16x8 a, bf16x8 b, f32x16 c) {
    return __builtin_amdgcn_mfma_f32_32x32x16_bf16(a, b, c, 0, 0, 0);
}
__device__ inline f32x16 zero16() {
    f32x16 z;
#pragma unroll
    for (int i = 0; i < 16; ++i) z[i] = 0.f;
    return z;
}
__device__ inline void gload_lds16(const void* g, void* l) {
    __builtin_amdgcn_global_load_lds(
        (const __attribute__((address_space(1))) void*)g,
        (__attribute__((address_space(3))) void*)l, 16, 0, 0);
}
__device__ inline void fence_vm0() {
    asm volatile("s_waitcnt vmcnt(0)" ::: "memory");
    __builtin_amdgcn_sched_barrier(0);
}
__device__ inline void fence_lgkm0() {
    asm volatile("s_waitcnt lgkmcnt(0)" ::: "memory");
    __builtin_amdgcn_sched_barrier(0);
}

// ---------------------------------------------------------------------------
// Pre-kernel 1 (R13 mapping): W1 emb range permuted
// (k0 = 64 + 8*(f-4) + 64*g); cont range and W2/W3/HW1 as R6.
// ---------------------------------------------------------------------------
__global__ __launch_bounds__(256) void build_wfrags(
    const float* __restrict__ W1, const float* __restrict__ W2,
    const float* __restrict__ W3, const float* __restrict__ HW1,
    ushort* __restrict__ WF)
{
    int gid = blockIdx.x * blockDim.x + threadIdx.x;
    if (gid >= kNFrag * 64) return;
    const int q = gid >> 6, l = gid & 63;
    const int lc = l & 31, g = l >> 5;

    const float* src; int k0, col, ldn, p;
    if (q < 12) {
        src = W1; col = lc; ldn = 32; p = 0;
        k0 = (q < 4) ? (16*q + 8*g) : (64 + 8*(q - 4) + 64*g);
    } else if (q < 24) {
        int f = q - 12;
        src = W1; col = lc; ldn = 32; p = 1;
        k0 = (f < 4) ? (16*f + 8*g) : (64 + 8*(f - 4) + 64*g);
    }
    else if (q < 28) { int u2 = q-24; src = W2; k0 = 16*(u2>>1) + 8*g; col = lc; ldn = 32; p = u2&1; }
    else if (q < 32) { int u2 = q-28; src = W3; k0 = 16*(u2>>1) + 8*g; col = lc; ldn = 32; p = u2&1; }
    else {
        int u2 = q-32; int n = u2>>2; int f = (u2>>1)&1; p = u2&1;
        int c128 = n*32 + lc; int head = c128 >> 4, ph = c128 & 15;
        src = HW1 + (size_t)head * kRH * kPH + ph;
        k0 = 16*f + 8*g; col = 0; ldn = kPH;
    }

    u32 hv[8];
#pragma unroll
    for (int j = 0; j < 8; ++j) {
        float w = src[(size_t)(k0 + j) * ldn + col];
        u32 h = rne_hi(w);
        hv[j] = (p == 0) ? h : rne_hi(w - hi_f32(h));
    }
    FragU fu;
#pragma unroll
    for (int w = 0; w < 4; ++w) fu.w[w] = hv[2*w] | (hv[2*w+1] << 16);
    ((uint4*)WF)[q * 64 + l] = fu.u4;
}

// ---------------------------------------------------------------------------
// Pre-kernel 2: emb -> bf16 HI-ONLY table, 16B records.
// ---------------------------------------------------------------------------
__global__ __launch_bounds__(256) void build_embhi(
    const float* __restrict__ emb, ushort* __restrict__ eh)
{
    int r = blockIdx.x * blockDim.x + threadIdx.x;
    if (r >= kNCate * kVocab) return;
    const float* e = emb + (size_t)r * kEm;
    FragU H;
#pragma unroll
    for (int w = 0; w < 4; ++w)
        H.w[w] = pack2(e[2*w], e[2*w+1]);
    ((uint4*)eh)[r] = H.u4;
}

// ---------------------------------------------------------------------------
// Transition (verified).
// ---------------------------------------------------------------------------
__device__ inline void transition(const float* v, int g, FragU* H, FragU* L) {
    u32 hw[8], lw[8];
#pragma unroll
    for (int p = 0; p < 8; ++p) {
        float v0 = v[2*p], v1 = v[2*p+1];
        u32 h0 = rne_hi(v0), h1 = rne_hi(v1);
        hw[p] = h0 | (h1 << 16);
        lw[p] = pack2(v0 - hi_f32(h0), v1 - hi_f32(h1));
    }
#pragma unroll
    for (int f2 = 0; f2 < 2; ++f2) {
        u32 hp[4], lp[4];
#pragma unroll
        for (int p = 0; p < 4; ++p) {
            hp[p] = (u32)__shfl_xor((int)hw[4*f2 + p], 32);
            lp[p] = (u32)__shfl_xor((int)lw[4*f2 + p], 32);
        }
        H[f2].w[0] = g ? hp[2] : hw[4*f2+0];
        H[f2].w[1] = g ? hp[3] : hw[4*f2+1];
        H[f2].w[2] = g ? hw[4*f2+2] : hp[0];
        H[f2].w[3] = g ? hw[4*f2+3] : hp[1];
        L[f2].w[0] = g ? lp[2] : lw[4*f2+0];
        L[f2].w[1] = g ? lp[3] : lw[4*f2+1];
        L[f2].w[2] = g ? lw[4*f2+2] : lp[0];
        L[f2].w[3] = g ? lw[4*f2+3] : lp[1];
    }
}

// ---------------------------------------------------------------------------
// Main kernel (R16 = best measured, 74.9 us): 2 tiles per wave, software-
// pipelined loads; 1 in-flight compute chain (no spill).
//   t1: stage+idx -> fence -> [issue emb1] cont1 -> [lgkm0, stage2+idx2]
//       emb1-MFMA, mid1 -> [issue emb2] heads1+store1 -> fence ->
//   t2: cont2, emb2-MFMA, mid2, heads2+store2.
// ---------------------------------------------------------------------------
__global__ __launch_bounds__(256, 3) void fused_main(
    const float* __restrict__ xc, const int* __restrict__ xcate,
    const int* __restrict__ tptr,
    const ushort* __restrict__ WF,
    const ushort* __restrict__ eh,
    const float* __restrict__ b1, const float* __restrict__ b2,
    const float* __restrict__ b3, const float* __restrict__ Hb1,
    const float* __restrict__ HW2, const float* __restrict__ Hb2,
    float* __restrict__ out)
{
    __shared__ __align__(16) uint4 sW4[16 * 64];      // 16 KB: W1hi 0..11, W1lo-cont 12..15
    __shared__ __align__(16) float sX[4][2048];       // 4 x 8KB x_cont stage
    __shared__ __align__(16) float sB[360];

    const int tid = threadIdx.x;
    const uint4* wf4 = (const uint4*)WF;

#pragma unroll
    for (int it = 0; it < 4; ++it) {
        const int i = tid + 256 * it;
        sW4[i] = wf4[i];
    }
    for (int i = tid; i < 360; i += 256) {
        float v;
        if      (i < 32)  v = b1[i];
        else if (i < 64)  v = b2[i - 32];
        else if (i < 96)  v = b3[i - 64];
        else if (i < 224) v = Hb1[i - 96];
        else if (i < 352) v = HW2[i - 224];
        else              v = Hb2[i - 352];
        sB[i] = v;
    }
    __syncthreads();

    const int wv = tid >> 6, l = tid & 63;
    const int lc = l & 31, g = l >> 5;
    const int rowbase = blockIdx.x * 256 + wv * 64;   // 2 tiles of 32
    char* xb = (char*)&sX[wv][0];
    const uint4* eh4 = (const uint4*)eh;

    // ---------------- helpers (lambdas, statically unrolled) ----------------
    auto stage_x = [&](int tbase) {
        const float* xbase = xc + (size_t)tbase * kCont;
#pragma unroll
        for (int i = 0; i < 8; ++i) {
            const int r   = 4*i + (l >> 4);
            const int c4s = (l & 15) ^ (r & 15);
            gload_lds16(xbase + r * kCont + c4s * 4, xb + i * 1024);
        }
    };
    auto load_idx = [&](int tbase, i32x4* iq, int& t_lane) {
        const i32x4* cr4 = (const i32x4*)(xcate + (size_t)(tbase + lc) * kNCate + 8*g);
        iq[0] = cr4[0];
        iq[1] = cr4[1];
        t_lane = tptr[tbase + lc];
    };
    auto gather_emb = [&](const i32x4* iq, uint4* ehv) {
#pragma unroll
        for (int i = 0; i < 8; ++i) {
            const int c   = i + 8*g;
            const int idx = (i < 4) ? iq[0][i] : iq[1][i - 4];
            ehv[i] = eh4[(size_t)(c * kVocab + idx)];
        }
    };
    auto layer1_cont = [&](f32x16& acca, f32x16& accb) {
#pragma unroll
        for (int f = 0; f < 4; ++f) {
            const int c0 = 4*f + 2*g;
            f32x4 va0 = *(const f32x4*)(xb + lc*256 + (((c0)     ^ (lc & 15)) * 16));
            f32x4 va1 = *(const f32x4*)(xb + lc*256 + (((c0 + 1) ^ (lc & 15)) * 16));
            FragU H, L;
#pragma unroll
            for (int w = 0; w < 4; ++w) {
                const f32x4& va = (w < 2) ? va0 : va1;
                const float v0 = va[2*(w & 1)], v1 = va[2*(w & 1) + 1];
                u32 h0 = rne_hi(v0), h1 = rne_hi(v1);
                H.w[w] = h0 | (h1 << 16);
                L.w[w] = pack2(v0 - hi_f32(h0), v1 - hi_f32(h1));
            }
            FragU WH, WL;
            WH.u4 = sW4[f * 64 + l];
            WL.u4 = sW4[(12 + f) * 64 + l];
            f32x16& acc = (f & 1) ? accb : acca;
            acc = mfma16(WH.v, H.v, acc);
            acc = mfma16(WL.v, H.v, acc);
            acc = mfma16(WH.v, L.v, acc);
        }
    };
    auto layer1_emb = [&](const uint4* ehv, f32x16& acca, f32x16& accb) {
#pragma unroll
        for (int i = 0; i < 8; ++i) {
            const int f = 4 + i;
            FragU BH, WH;
            BH.u4 = ehv[i];
            WH.u4 = sW4[f * 64 + l];
            f32x16& acc = (f & 1) ? accb : acca;
            acc = mfma16(WH.v, BH.v, acc);
        }
    };
    auto mid = [&](const f32x16& acca, const f32x16& accb, FragU* a4h, FragU* a4l) {
        float v1v[16];
#pragma unroll
        for (int p = 0; p < 4; ++p) {
            f32x4 bq = *(const f32x4*)&sB[0 + 8*p + 4*g];
#pragma unroll
            for (int m = 0; m < 4; ++m)
                v1v[4*p + m] = fmaxf(acca[4*p + m] + accb[4*p + m] + bq[m], 0.f);
        }
        FragU a2h[2], a2l[2];
        transition(v1v, g, a2h, a2l);

        f32x16 acc2 = zero16();
#pragma unroll
        for (int f2 = 0; f2 < 2; ++f2) {
            FragU WH, WL;
            WH.u4 = wf4[(24 + 2*f2) * 64 + l];
            WL.u4 = wf4[(25 + 2*f2) * 64 + l];
            acc2 = mfma16(WH.v, a2h[f2].v, acc2);
            acc2 = mfma16(WL.v, a2h[f2].v, acc2);
            acc2 = mfma16(WH.v, a2l[f2].v, acc2);
        }
        float v2v[16];
#pragma unroll
        for (int p = 0; p < 4; ++p) {
            f32x4 bq = *(const f32x4*)&sB[32 + 8*p + 4*g];
#pragma unroll
            for (int m = 0; m < 4; ++m)
                v2v[4*p + m] = fmaxf(acc2[4*p + m] + bq[m], 0.f);
        }
        FragU a3h[2], a3l[2];
        transition(v2v, g, a3h, a3l);

        f32x16 acc3 = zero16();
#pragma unroll
        for (int f2 = 0; f2 < 2; ++f2) {
            FragU WH, WL;
            WH.u4 = wf4[(28 + 2*f2) * 64 + l];
            WL.u4 = wf4[(29 + 2*f2) * 64 + l];
            acc3 = mfma16(WH.v, a3h[f2].v, acc3);
            acc3 = mfma16(WL.v, a3h[f2].v, acc3);
            acc3 = mfma16(WH.v, a3l[f2].v, acc3);
        }
        float v3v[16];
#pragma unroll
        for (int p = 0; p < 4; ++p) {
            f32x4 bq = *(const f32x4*)&sB[64 + 8*p + 4*g];
#pragma unroll
            for (int m = 0; m < 4; ++m)
                v3v[4*p + m] = acc3[4*p + m] + bq[m];
        }
        transition(v3v, g, a4h, a4l);
    };
    auto heads_store = [&](const FragU* a4h, const FragU* a4l, int t_lane, int arow) {
        const f32x4 hb1q0 = *(const f32x4*)&sB[96  + t_lane*16 + 4*g];
        const f32x4 hb1q1 = *(const f32x4*)&sB[96  + t_lane*16 + 8 + 4*g];
        const f32x4 hw2q0 = *(const f32x4*)&sB[224 + t_lane*16 + 4*g];
        const f32x4 hw2q1 = *(const f32x4*)&sB[224 + t_lane*16 + 8 + 4*g];

        float ys = 0.f;
#pragma unroll
        for (int n = 0; n < 4; ++n) {
            f32x16 hacc = zero16();
#pragma unroll
            for (int f2 = 0; f2 < 2; ++f2) {
                FragU WH, WL;
                WH.u4 = wf4[(32 + 4*n + 2*f2) * 64 + l];
                WL.u4 = wf4[(33 + 4*n + 2*f2) * 64 + l];
                hacc = mfma16(WH.v, a4h[f2].v, hacc);
                hacc = mfma16(WL.v, a4h[f2].v, hacc);
                hacc = mfma16(WH.v, a4l[f2].v, hacc);
            }
            const bool sel = ((t_lane >> 1) == n);
            const bool half = (t_lane & 1);
#pragma unroll
            for (int j = 0; j < 8; ++j) {
                const float bb = (j < 4) ? hb1q0[j] : hb1q1[j - 4];
                const float ww = (j < 4) ? hw2q0[j] : hw2q1[j - 4];
                const float c0 = fmaxf(hacc[j]     + bb, 0.f) * ww;
                const float c1 = fmaxf(hacc[8 + j] + bb, 0.f) * ww;
                const float pick = half ? c1 : c0;
                ys += sel ? pick : 0.f;
            }
        }
        const float ytot = ys + __shfl_xor(ys, 32);
        if (g == 0)
            out[arow] = ytot + sB[352 + t_lane];
    };

    // ---------------- pipelined 2-tile schedule ----------------
    const int tb1 = rowbase, tb2 = rowbase + 32;

    stage_x(tb1);
    i32x4 iq1[2]; int t1;
    load_idx(tb1, iq1, t1);

    fence_vm0();                      // xb(t1) + iq1 + t1 ready

    uint4 ehv1[8];
    gather_emb(iq1, ehv1);            // in flight under cont1

    f32x16 acca = zero16(), accb = zero16();
    layer1_cont(acca, accb);

    fence_lgkm0();                    // xb ds_reads retired -> safe to overwrite
    stage_x(tb2);                     // tile-2 staging flies under t1 compute
    i32x4 iq2[2]; int t2;
    load_idx(tb2, iq2, t2);

    layer1_emb(ehv1, acca, accb);     // compiler waits ehv1 here
    FragU a4h[2], a4l[2];
    mid(acca, accb, a4h, a4l);

    uint4 ehv2[8];
    gather_emb(iq2, ehv2);            // in flight under heads1

    heads_store(a4h, a4l, t1, tb1 + lc);

    fence_vm0();                      // xb(t2) ready (ehv2 likely landed too)

    acca = zero16(); accb = zero16();
    layer1_cont(acca, accb);
    layer1_emb(ehv2, acca, accb);
    mid(acca, accb, a4h, a4l);
    heads_store(a4h, a4l, t2, tb2 + lc);
}

} // namespace

extern "C" void kernel_launch(void* const* d_in, const int* in_sizes, int n_in,
                              void* d_out, int out_size, void* d_ws, size_t ws_size,
                              hipStream_t stream)
{
    const float* x_cont = (const float*)d_in[0];
    const int*   x_cate = (const int*)  d_in[1];
    const int*   t      = (const int*)  d_in[2];
    const float* emb    = (const float*)d_in[3];
    const float* W1     = (const float*)d_in[4];
    const float* b1     = (const float*)d_in[5];
    const float* W2     = (const float*)d_in[6];
    const float* b2     = (const float*)d_in[7];
    const float* W3     = (const float*)d_in[8];
    const float* b3     = (const float*)d_in[9];
    const float* HW1    = (const float*)d_in[10];
    const float* Hb1    = (const float*)d_in[11];
    const float* HW2    = (const float*)d_in[12];
    const float* Hb2    = (const float*)d_in[13];
    float* out = (float*)d_out;

    ushort* WF = (ushort*)d_ws;
    ushort* eh = (ushort*)((char*)d_ws + kOffEH);

    hipLaunchKernelGGL(build_wfrags, dim3(12), dim3(256), 0, stream, W1, W2, W3, HW1, WF);
    hipLaunchKernelGGL(build_embhi, dim3((kNCate*kVocab + 255)/256), dim3(256), 0, stream,
                       emb, eh);

    const int grid = kRows / 256;   // 2048 blocks; 4 waves x 2 tiles x 32 rows
    hipLaunchKernelGGL(fused_main, dim3(grid), dim3(256), 0, stream,
                       x_cont, x_cate, t, WF, eh,
                       b1, b2, b3, Hb1, HW2, Hb2, out);
}